// Round 8
// baseline (231.881 us; speedup 1.0000x reference)
//
#include <hip/hip_runtime.h>

#define F_DIM 128
#define TE_DIM 32
#define DD 160
#define NB 4096
#define KK 64
#define LD 164        // padded fp32 LDS row stride
#define TE_STRIDE 36  // padded half stride (18 dwords; 2-way max on reads, free)
#define XH_STRIDE 134 // staged fp16 row stride: 67 dwords (odd) -> writes 2-way, reads conflict-free

// ws layout (float offsets)
#define WS_M   0          // [160][160]  (Wk^T Wq) / sqrt(160)
#define WS_V2  25600      // [160][160]  out_w @ Wv
#define WS_C   51200      // [160]       (Wk^T bq) / sqrt(160)
#define WS_U   51360      // [160]       (Wq^T bk) / sqrt(160)
#define WS_B2  51520      // [160]       out_w @ bv + out_b
#define WS_S0  51680      // [1]         (bq . bk) / sqrt(160)
#define WS_TE  51684      // [10000][32] cos(t*te_w[d]+te_b[d])
#define TAB_T  10000
#define TAB_N  (TAB_T * TE_DIM)
#define TAB_BLOCKS 250
#define SETUP_BASE (2 * DD + 3)

__device__ __forceinline__ float dot4acc(const float4 w, const float4 v, float a) {
    a = fmaf(w.x, v.x, a);
    a = fmaf(w.y, v.y, a);
    a = fmaf(w.z, v.z, a);
    a = fmaf(w.w, v.w, a);
    return a;
}

__device__ __forceinline__ float wave_max(float v) {
    #pragma unroll
    for (int off = 32; off > 0; off >>= 1) v = fmaxf(v, __shfl_xor(v, off, 64));
    return v;
}
__device__ __forceinline__ float wave_sum(float v) {
    #pragma unroll
    for (int off = 32; off > 0; off >>= 1) v += __shfl_xor(v, off, 64);
    return v;
}

// ---------------- setup: fold weight matrices + te table -------------------
__global__ __launch_bounds__(256)
void setup_kernel(const float* __restrict__ ipw, const float* __restrict__ ipb,
                  const float* __restrict__ ow,  const float* __restrict__ ob,
                  const float* __restrict__ te_w, const float* __restrict__ te_b,
                  float* __restrict__ ws)
{
    const int blk = blockIdx.x;
    const int t   = threadIdx.x;
    const float inv = 0.07905694150420949f;  // 1/sqrt(160)

    __shared__ float s_vec[DD];

    if (blk >= SETUP_BASE) {
        const int g0 = (blk - SETUP_BASE) * 256 + t;
        #pragma unroll
        for (int it = 0; it < 5; ++it) {
            const int g = g0 + it * (TAB_BLOCKS * 256);
            const int tt = g >> 5, d = g & 31;
            ws[WS_TE + g] = cosf(fmaf((float)tt, te_w[d], te_b[d]));
        }
        return;
    }

    if (blk < DD) {
        const float* wk = ipw + DD * DD;
        if (t < DD) s_vec[t] = wk[(long)t * DD + blk];
        __syncthreads();
        if (t < DD) {
            float a0 = 0.f, a1 = 0.f, a2 = 0.f, a3 = 0.f;
            #pragma unroll 4
            for (int d = 0; d < DD; d += 4) {
                a0 = fmaf(s_vec[d],     ipw[(long)d * DD + t],       a0);
                a1 = fmaf(s_vec[d + 1], ipw[(long)(d + 1) * DD + t], a1);
                a2 = fmaf(s_vec[d + 2], ipw[(long)(d + 2) * DD + t], a2);
                a3 = fmaf(s_vec[d + 3], ipw[(long)(d + 3) * DD + t], a3);
            }
            ws[WS_M + blk * DD + t] = (a0 + a1 + a2 + a3) * inv;
        }
    } else if (blk < 2 * DD) {
        const int i = blk - DD;
        const float* wv = ipw + 2 * DD * DD;
        if (t < DD) s_vec[t] = ow[(long)i * DD + t];
        __syncthreads();
        if (t < DD) {
            float a0 = 0.f, a1 = 0.f, a2 = 0.f, a3 = 0.f;
            #pragma unroll 4
            for (int d = 0; d < DD; d += 4) {
                a0 = fmaf(s_vec[d],     wv[(long)d * DD + t],       a0);
                a1 = fmaf(s_vec[d + 1], wv[(long)(d + 1) * DD + t], a1);
                a2 = fmaf(s_vec[d + 2], wv[(long)(d + 2) * DD + t], a2);
                a3 = fmaf(s_vec[d + 3], wv[(long)(d + 3) * DD + t], a3);
            }
            ws[WS_V2 + i * DD + t] = a0 + a1 + a2 + a3;
        }
    } else if (blk == 2 * DD) {
        const float* wk = ipw + DD * DD;
        if (t < DD) s_vec[t] = ipb[t];
        __syncthreads();
        if (t < DD) {
            float a0 = 0.f, a1 = 0.f, a2 = 0.f, a3 = 0.f;
            #pragma unroll 4
            for (int d = 0; d < DD; d += 4) {
                a0 = fmaf(s_vec[d],     wk[(long)d * DD + t],       a0);
                a1 = fmaf(s_vec[d + 1], wk[(long)(d + 1) * DD + t], a1);
                a2 = fmaf(s_vec[d + 2], wk[(long)(d + 2) * DD + t], a2);
                a3 = fmaf(s_vec[d + 3], wk[(long)(d + 3) * DD + t], a3);
            }
            ws[WS_C + t] = (a0 + a1 + a2 + a3) * inv;
        }
    } else if (blk == 2 * DD + 1) {
        if (t < DD) s_vec[t] = ipb[DD + t];
        __syncthreads();
        if (t < DD) {
            float a0 = 0.f, a1 = 0.f, a2 = 0.f, a3 = 0.f;
            #pragma unroll 4
            for (int d = 0; d < DD; d += 4) {
                a0 = fmaf(s_vec[d],     ipw[(long)d * DD + t],       a0);
                a1 = fmaf(s_vec[d + 1], ipw[(long)(d + 1) * DD + t], a1);
                a2 = fmaf(s_vec[d + 2], ipw[(long)(d + 2) * DD + t], a2);
                a3 = fmaf(s_vec[d + 3], ipw[(long)(d + 3) * DD + t], a3);
            }
            ws[WS_U + t] = (a0 + a1 + a2 + a3) * inv;
        }
    } else {
        if (t < DD) s_vec[t] = ipb[2 * DD + t];
        __syncthreads();
        if (t < DD) {
            const float* owr = ow + (long)t * DD;
            float a0 = 0.f, a1 = 0.f, a2 = 0.f, a3 = 0.f;
            #pragma unroll 4
            for (int d = 0; d < DD; d += 4) {
                a0 = fmaf(s_vec[d],     owr[d],     a0);
                a1 = fmaf(s_vec[d + 1], owr[d + 1], a1);
                a2 = fmaf(s_vec[d + 2], owr[d + 2], a2);
                a3 = fmaf(s_vec[d + 3], owr[d + 3], a3);
            }
            ws[WS_B2 + t] = ob[t] + (a0 + a1 + a2 + a3);
        }
        if (t >= 192) {
            const int lane = t - 192;
            float p = ipb[lane] * ipb[DD + lane];
            p = fmaf(ipb[lane + 64], ipb[DD + lane + 64], p);
            if (lane < 32) p = fmaf(ipb[lane + 128], ipb[DD + lane + 128], p);
            const float s = wave_sum(p);
            if (lane == 0) ws[WS_S0] = s * inv;
        }
    }
}

// ---------------- main ------------------------------------------------------
// ONE batch row per 256-thread block (4 waves). Wave w:
//   P2a: feature-quarter w of all 64 scores + write-through fp16 stage of that
//        quarter into s_xh (x touched ONCE from global).
//   P3 : k-quarter w of the wkv partial, read from s_xh.
// LDS ~28 KB -> 5 blocks/CU; VGPR capped 102 via launch_bounds -> 20 waves/CU.
__global__ __launch_bounds__(256, 5)
void structure_learner_kernel(
    const float* __restrict__ x,
    const int*   __restrict__ target_node_ids,
    const int*   __restrict__ target_node_times,
    const int*   __restrict__ neighbor_ids,
    const int*   __restrict__ edge_time,
    const float* __restrict__ edge_weight,
    const float* __restrict__ gumbel_u,
    const float* __restrict__ te_w,
    const float* __restrict__ te_b,
    const float* __restrict__ mlp_w,
    const float* __restrict__ mlp_b,
    const float* __restrict__ ws,
    const float* __restrict__ tetab,   // nullptr -> cos in-kernel
    float* __restrict__ out_ao,
    float* __restrict__ out_new,
    float* __restrict__ out_mask)
{
    __shared__ __attribute__((aligned(16))) _Float16 s_xh[KK][XH_STRIDE];
    __shared__ __attribute__((aligned(16))) float s_qin[LD];
    __shared__ __attribute__((aligned(16))) float s_qt[LD];
    __shared__ __attribute__((aligned(16))) float s_wkvp[4][LD];
    __shared__ __attribute__((aligned(16))) float s_ao[LD];
    __shared__ float s_scp[4][KK];     // partial scores per feature-quarter
    __shared__ float s_attnw[4][KK];   // per-wave attn copies
    __shared__ __attribute__((aligned(4))) _Float16 s_te[KK][TE_STRIDE];

    const int tid  = threadIdx.x;
    const int w    = tid >> 6;   // wave 0..3 = quarter
    const int lane = tid & 63;
    const int b    = blockIdx.x;

    const float* Mw = ws + WS_M;
    const float* V2 = ws + WS_V2;
    const float* Cv = ws + WS_C;
    const float* Uv = ws + WS_U;
    const float* B2 = ws + WS_B2;
    const float  s0 = ws[WS_S0];

    // this lane's neighbor id (same across the 4 waves; coalesced, L2-hot)
    const int nid_l = neighbor_ids[(long)b * KK + lane];

    // ---- P0: q_in + te rows ----
    {
        if (w == 0) {
            const int tn = target_node_ids[b];
            const float2 tx = *(const float2*)(x + (long)tn * F_DIM + lane * 2);
            s_qin[lane * 2]     = tx.x;
            s_qin[lane * 2 + 1] = tx.y;
        } else if (w == 1 && lane < TE_DIM) {
            const int tt = target_node_times[b];
            s_qin[F_DIM + lane] =
                (tetab && (unsigned)tt < (unsigned)TAB_T)
                    ? tetab[(long)tt * TE_DIM + lane]
                    : cosf(fmaf((float)tt, te_w[lane], te_b[lane]));
        }
        // te fill: thread t covers k = t>>2, dims [8j, 8j+8)
        const int k = tid >> 2, j = tid & 3;
        const int etv_i = edge_time[(long)b * KK + k];
        if (tetab && (unsigned)etv_i < (unsigned)TAB_T) {
            const float4* trow = (const float4*)(tetab + (long)etv_i * TE_DIM) + 2 * j;
            const float4 t0 = trow[0], t1 = trow[1];
            union { _Float16 h2[2]; unsigned u; } p0, p1, p2, p3;
            p0.h2[0] = (_Float16)t0.x; p0.h2[1] = (_Float16)t0.y;
            p1.h2[0] = (_Float16)t0.z; p1.h2[1] = (_Float16)t0.w;
            p2.h2[0] = (_Float16)t1.x; p2.h2[1] = (_Float16)t1.y;
            p3.h2[0] = (_Float16)t1.z; p3.h2[1] = (_Float16)t1.w;
            *(unsigned*)&s_te[k][8 * j]     = p0.u;
            *(unsigned*)&s_te[k][8 * j + 2] = p1.u;
            *(unsigned*)&s_te[k][8 * j + 4] = p2.u;
            *(unsigned*)&s_te[k][8 * j + 6] = p3.u;
        } else {
            const float etv = (float)etv_i;
            #pragma unroll
            for (int ii = 0; ii < 4; ++ii) {
                const int d0 = 8 * j + 2 * ii;
                union { _Float16 h2[2]; unsigned u; } pk;
                pk.h2[0] = (_Float16)cosf(fmaf(etv, te_w[d0],     te_b[d0]));
                pk.h2[1] = (_Float16)cosf(fmaf(etv, te_w[d0 + 1], te_b[d0 + 1]));
                *(unsigned*)&s_te[k][d0] = pk.u;
            }
        }
    }
    __syncthreads();

    // ---- P1: q_tilde = M @ q_in + c (threads 0..159, one output each) ----
    if (tid < DD) {
        const float4* v4   = (const float4*)s_qin;
        const float4* wrow = (const float4*)(Mw + (long)tid * DD);
        float a0 = Cv[tid];
        #pragma unroll 8
        for (int f = 0; f < 40; ++f) a0 = dot4acc(wrow[f], v4[f], a0);
        s_qt[tid] = a0;
    }
    __syncthreads();

    // ---- P2a: partial scores (quarter w) + write-through fp16 staging ----
    {
        const int fo = 32 * w;
        const float4* xr  = (const float4*)(x + (long)nid_l * F_DIM + fo);
        const float4* qt4 = (const float4*)(s_qt + fo);
        _Float16* st = &s_xh[lane][fo];
        float acc0 = 0.f, acc1 = 0.f;
        #pragma unroll
        for (int f = 0; f < 8; f += 2) {
            const float4 a = xr[f], c = xr[f + 1];
            acc0 = dot4acc(a, qt4[f],     acc0);
            acc1 = dot4acc(c, qt4[f + 1], acc1);
            union { _Float16 hh[4]; unsigned long long u; } pa, pb;
            pa.hh[0] = (_Float16)a.x; pa.hh[1] = (_Float16)a.y;
            pa.hh[2] = (_Float16)a.z; pa.hh[3] = (_Float16)a.w;
            pb.hh[0] = (_Float16)c.x; pb.hh[1] = (_Float16)c.y;
            pb.hh[2] = (_Float16)c.z; pb.hh[3] = (_Float16)c.w;
            *(unsigned long long*)&st[4 * f]     = pa.u;
            *(unsigned long long*)&st[4 * f + 4] = pb.u;
        }
        float acc = acc0 + acc1;
        if (w == 0) {
            // te-part + folded bias terms into quarter 0's partial
            const float* qte = s_qt + F_DIM;
            #pragma unroll
            for (int jj = 0; jj < 16; ++jj) {
                union { _Float16 h2[2]; unsigned u; } pk;
                pk.u = *(const unsigned*)&s_te[lane][2 * jj];
                acc = fmaf(qte[2 * jj],     (float)pk.h2[0], acc);
                acc = fmaf(qte[2 * jj + 1], (float)pk.h2[1], acc);
            }
            float p = s_qin[lane] * Uv[lane];
            p = fmaf(s_qin[lane + 64], Uv[lane + 64], p);
            if (lane < 32) p = fmaf(s_qin[128 + lane], Uv[128 + lane], p);
            acc += wave_sum(p) + s0;
        }
        s_scp[w][lane] = acc;
    }
    __syncthreads();

    // ---- P2b: merge + softmax (redundant in all 4 waves, bit-identical) ----
    float aw;
    {
        const float sc = s_scp[0][lane] + s_scp[1][lane]
                       + s_scp[2][lane] + s_scp[3][lane];
        const float m = wave_max(sc);
        const float e = expf(sc - m);
        const float l = wave_sum(e);
        aw = e / l;
        s_attnw[w][lane] = aw;   // own-wave copy: no barrier needed
    }

    // ---- P3: partial wkv from the LDS stage (k-quarter w) ----
    {
        float ax = 0.f, ay = 0.f, at = 0.f;
        const int lte = lane & 31;
        #pragma unroll
        for (int q = 0; q < 16; ++q) {
            const int kq = 16 * w + q;
            const float wgt = s_attnw[w][kq];
            union { unsigned u; _Float16 h2[2]; } c;
            c.u = *(const unsigned*)&s_xh[kq][2 * lane];
            ax = fmaf(wgt, (float)c.h2[0], ax);
            ay = fmaf(wgt, (float)c.h2[1], ay);
            at = fmaf(wgt, (float)s_te[kq][lte], at);
        }
        s_wkvp[w][lane * 2]     = ax;
        s_wkvp[w][lane * 2 + 1] = ay;
        if (lane < TE_DIM) s_wkvp[w][F_DIM + lane] = at;
    }
    __syncthreads();

    // ---- prefetch P5 inputs for the epilogue wave (hide under P4) ----
    float u = 0.f, ew = 0.f;
    if (w == 0) {
        u  = gumbel_u[(long)b * KK + lane];
        ew = edge_weight[(long)b * KK + lane];
    }

    // ---- P4: ao = V2 @ (sum of 4 wkv partials) + b2 ----
    if (tid < DD) {
        const float4* wrow = (const float4*)(V2 + (long)tid * DD);
        const float4* p0 = (const float4*)s_wkvp[0];
        const float4* p1 = (const float4*)s_wkvp[1];
        const float4* p2 = (const float4*)s_wkvp[2];
        const float4* p3 = (const float4*)s_wkvp[3];
        float a0 = B2[tid];
        #pragma unroll 4
        for (int f = 0; f < 40; ++f) {
            const float4 A = p0[f], Bv = p1[f], C = p2[f], Dv = p3[f];
            float4 v;
            v.x = (A.x + Bv.x) + (C.x + Dv.x);
            v.y = (A.y + Bv.y) + (C.y + Dv.y);
            v.z = (A.z + Bv.z) + (C.z + Dv.z);
            v.w = (A.w + Bv.w) + (C.w + Dv.w);
            a0 = dot4acc(wrow[f], v, a0);
        }
        s_ao[tid] = a0;
    }
    __syncthreads();

    // ---- P5: epilogue (wave 0; it holds aw for all 64 k) ----
    if (w == 0) {
        float p = s_ao[lane] * mlp_w[lane];
        p = fmaf(s_ao[lane + 64], mlp_w[lane + 64], p);
        if (lane < 32) p = fmaf(s_ao[lane + 128], mlp_w[lane + 128], p);
        const float base = wave_sum(p) + mlp_b[0];

        float* ao = out_ao + (long)b * DD;
        ao[lane]      = s_ao[lane];
        ao[lane + 64] = s_ao[lane + 64];
        if (lane < 32) ao[lane + 128] = s_ao[lane + 128];

        const float g = -logf(-logf(u + 1e-10f) + 1e-10f);
        const float z = aw + g;  // TAU = 1.0
        const float m = wave_max(z);
        const float e = expf(z - m);
        const float l = wave_sum(e);
        out_mask[(long)b * KK + lane] = (e / l > 0.2f) ? 1.0f : 0.0f;

        const float val = fmaf(ew, mlp_w[DD], base);
        out_new[(long)b * KK + lane] = (val >= 0.f) ? val : 0.01f * val;
    }
}

extern "C" void kernel_launch(void* const* d_in, const int* in_sizes, int n_in,
                              void* d_out, int out_size, void* d_ws, size_t ws_size,
                              hipStream_t stream) {
    const float* x   = (const float*)d_in[0];
    const int*   tni = (const int*)d_in[1];
    const int*   tnt = (const int*)d_in[2];
    const int*   nid = (const int*)d_in[3];
    const int*   et  = (const int*)d_in[4];
    const float* ew  = (const float*)d_in[5];
    const float* gu  = (const float*)d_in[6];
    const float* tew = (const float*)d_in[7];
    const float* teb = (const float*)d_in[8];
    const float* ipw = (const float*)d_in[9];
    const float* ipb = (const float*)d_in[10];
    const float* ow  = (const float*)d_in[11];
    const float* ob  = (const float*)d_in[12];
    const float* mw  = (const float*)d_in[13];
    const float* mb  = (const float*)d_in[14];

    float* wsf = (float*)d_ws;

    float* out      = (float*)d_out;
    float* out_ao   = out;
    float* out_new  = out + (long)NB * DD;
    float* out_mask = out + (long)NB * DD + (long)NB * KK;

    const bool use_tab = ws_size >= (size_t)(WS_TE + TAB_N) * sizeof(float);
    const int  setup_grid = SETUP_BASE + (use_tab ? TAB_BLOCKS : 0);

    setup_kernel<<<setup_grid, 256, 0, stream>>>(ipw, ipb, ow, ob, tew, teb, wsf);

    structure_learner_kernel<<<NB, 256, 0, stream>>>(
        x, tni, tnt, nid, et, ew, gu, tew, teb, mw, mb, wsf,
        use_tab ? (wsf + WS_TE) : nullptr,
        out_ao, out_new, out_mask);
}

// Round 10
// 162.944 us; speedup vs baseline: 1.4231x; 1.4231x over previous
//
#include <hip/hip_runtime.h>

#define F_DIM 128
#define TE_DIM 32
#define DD 160
#define NB 4096
#define KK 64
#define ROWS 4
#define LD 164         // padded fp32 LDS row stride
#define XH_STRIDE 168  // staged fp16 row stride (84 dwords; 16B-aligned rows)
#define KT 16          // k-tile size (4 tiles)

// ws layout (float offsets)
#define WS_M   0          // [160][160]  (Wk^T Wq) / sqrt(160)
#define WS_V2  25600      // [160][160]  out_w @ Wv
#define WS_C   51200      // [160]       (Wk^T bq) / sqrt(160)
#define WS_U   51360      // [160]       (Wq^T bk) / sqrt(160)
#define WS_B2  51520      // [160]       out_w @ bv + out_b
#define WS_S0  51680      // [1]         (bq . bk) / sqrt(160)
#define WS_TE  51684      // [10000][32] cos(t*te_w[d]+te_b[d])
#define TAB_T  10000
#define TAB_N  (TAB_T * TE_DIM)
#define TAB_BLOCKS 250
#define SETUP_BASE (2 * DD + 3)

__device__ __forceinline__ float dot4acc(const float4 w, const float4 v, float a) {
    a = fmaf(w.x, v.x, a);
    a = fmaf(w.y, v.y, a);
    a = fmaf(w.z, v.z, a);
    a = fmaf(w.w, v.w, a);
    return a;
}

__device__ __forceinline__ float wave_max(float v) {
    #pragma unroll
    for (int off = 32; off > 0; off >>= 1) v = fmaxf(v, __shfl_xor(v, off, 64));
    return v;
}
__device__ __forceinline__ float wave_sum(float v) {
    #pragma unroll
    for (int off = 32; off > 0; off >>= 1) v += __shfl_xor(v, off, 64);
    return v;
}

// Block-cooperative GEMV (R1-proven): r = tid&3, dl = tid>>2.
// Lanes 4t..4t+3 share weight addresses -> 4:1 dedup in the coalescer.
__device__ __forceinline__ void gemv_rows(
    const float* __restrict__ W, const float* __restrict__ bias,
    const float (*vin)[LD], float (*vout)[LD], int tid)
{
    const int r  = tid & 3;
    const int dl = tid >> 2;
    const float4* v4 = (const float4*)vin[r];
    const float4* w0 = (const float4*)(W + (long)dl * DD);
    const float4* w1 = (const float4*)(W + (long)(dl + 64) * DD);
    float a0 = bias[dl];
    float a1 = bias[dl + 64];
    if (dl < 32) {
        const float4* w2 = (const float4*)(W + (long)(dl + 128) * DD);
        float a2 = bias[dl + 128];
        #pragma unroll 8
        for (int f = 0; f < 40; ++f) {
            const float4 v = v4[f];
            a0 = dot4acc(w0[f], v, a0);
            a1 = dot4acc(w1[f], v, a1);
            a2 = dot4acc(w2[f], v, a2);
        }
        vout[r][dl]       = a0;
        vout[r][dl + 64]  = a1;
        vout[r][dl + 128] = a2;
    } else {
        #pragma unroll 8
        for (int f = 0; f < 40; ++f) {
            const float4 v = v4[f];
            a0 = dot4acc(w0[f], v, a0);
            a1 = dot4acc(w1[f], v, a1);
        }
        vout[r][dl]      = a0;
        vout[r][dl + 64] = a1;
    }
}

// ---------------- setup: fold weight matrices + te table -------------------
__global__ __launch_bounds__(256)
void setup_kernel(const float* __restrict__ ipw, const float* __restrict__ ipb,
                  const float* __restrict__ ow,  const float* __restrict__ ob,
                  const float* __restrict__ te_w, const float* __restrict__ te_b,
                  float* __restrict__ ws)
{
    const int blk = blockIdx.x;
    const int t   = threadIdx.x;
    const float inv = 0.07905694150420949f;  // 1/sqrt(160)

    __shared__ float s_vec[DD];

    if (blk >= SETUP_BASE) {
        const int g0 = (blk - SETUP_BASE) * 256 + t;
        #pragma unroll
        for (int it = 0; it < 5; ++it) {
            const int g = g0 + it * (TAB_BLOCKS * 256);
            const int tt = g >> 5, d = g & 31;
            ws[WS_TE + g] = cosf(fmaf((float)tt, te_w[d], te_b[d]));
        }
        return;
    }

    if (blk < DD) {
        const float* wk = ipw + DD * DD;
        if (t < DD) s_vec[t] = wk[(long)t * DD + blk];
        __syncthreads();
        if (t < DD) {
            float a0 = 0.f, a1 = 0.f, a2 = 0.f, a3 = 0.f;
            #pragma unroll 4
            for (int d = 0; d < DD; d += 4) {
                a0 = fmaf(s_vec[d],     ipw[(long)d * DD + t],       a0);
                a1 = fmaf(s_vec[d + 1], ipw[(long)(d + 1) * DD + t], a1);
                a2 = fmaf(s_vec[d + 2], ipw[(long)(d + 2) * DD + t], a2);
                a3 = fmaf(s_vec[d + 3], ipw[(long)(d + 3) * DD + t], a3);
            }
            ws[WS_M + blk * DD + t] = (a0 + a1 + a2 + a3) * inv;
        }
    } else if (blk < 2 * DD) {
        const int i = blk - DD;
        const float* wv = ipw + 2 * DD * DD;
        if (t < DD) s_vec[t] = ow[(long)i * DD + t];
        __syncthreads();
        if (t < DD) {
            float a0 = 0.f, a1 = 0.f, a2 = 0.f, a3 = 0.f;
            #pragma unroll 4
            for (int d = 0; d < DD; d += 4) {
                a0 = fmaf(s_vec[d],     wv[(long)d * DD + t],       a0);
                a1 = fmaf(s_vec[d + 1], wv[(long)(d + 1) * DD + t], a1);
                a2 = fmaf(s_vec[d + 2], wv[(long)(d + 2) * DD + t], a2);
                a3 = fmaf(s_vec[d + 3], wv[(long)(d + 3) * DD + t], a3);
            }
            ws[WS_V2 + i * DD + t] = a0 + a1 + a2 + a3;
        }
    } else if (blk == 2 * DD) {
        const float* wk = ipw + DD * DD;
        if (t < DD) s_vec[t] = ipb[t];
        __syncthreads();
        if (t < DD) {
            float a0 = 0.f, a1 = 0.f, a2 = 0.f, a3 = 0.f;
            #pragma unroll 4
            for (int d = 0; d < DD; d += 4) {
                a0 = fmaf(s_vec[d],     wk[(long)d * DD + t],       a0);
                a1 = fmaf(s_vec[d + 1], wk[(long)(d + 1) * DD + t], a1);
                a2 = fmaf(s_vec[d + 2], wk[(long)(d + 2) * DD + t], a2);
                a3 = fmaf(s_vec[d + 3], wk[(long)(d + 3) * DD + t], a3);
            }
            ws[WS_C + t] = (a0 + a1 + a2 + a3) * inv;
        }
    } else if (blk == 2 * DD + 1) {
        if (t < DD) s_vec[t] = ipb[DD + t];
        __syncthreads();
        if (t < DD) {
            float a0 = 0.f, a1 = 0.f, a2 = 0.f, a3 = 0.f;
            #pragma unroll 4
            for (int d = 0; d < DD; d += 4) {
                a0 = fmaf(s_vec[d],     ipw[(long)d * DD + t],       a0);
                a1 = fmaf(s_vec[d + 1], ipw[(long)(d + 1) * DD + t], a1);
                a2 = fmaf(s_vec[d + 2], ipw[(long)(d + 2) * DD + t], a2);
                a3 = fmaf(s_vec[d + 3], ipw[(long)(d + 3) * DD + t], a3);
            }
            ws[WS_U + t] = (a0 + a1 + a2 + a3) * inv;
        }
    } else {
        if (t < DD) s_vec[t] = ipb[2 * DD + t];
        __syncthreads();
        if (t < DD) {
            const float* owr = ow + (long)t * DD;
            float a0 = 0.f, a1 = 0.f, a2 = 0.f, a3 = 0.f;
            #pragma unroll 4
            for (int d = 0; d < DD; d += 4) {
                a0 = fmaf(s_vec[d],     owr[d],     a0);
                a1 = fmaf(s_vec[d + 1], owr[d + 1], a1);
                a2 = fmaf(s_vec[d + 2], owr[d + 2], a2);
                a3 = fmaf(s_vec[d + 3], owr[d + 3], a3);
            }
            ws[WS_B2 + t] = ob[t] + (a0 + a1 + a2 + a3);
        }
        if (t >= 192) {
            const int lane = t - 192;
            float p = ipb[lane] * ipb[DD + lane];
            p = fmaf(ipb[lane + 64], ipb[DD + lane + 64], p);
            if (lane < 32) p = fmaf(ipb[lane + 128], ipb[DD + lane + 128], p);
            const float s = wave_sum(p);
            if (lane == 0) ws[WS_S0] = s * inv;
        }
    }
}

// ---------------- main ------------------------------------------------------
// R1 shell: ROWS=4, 256 threads, wave = row, grid 1024, 4-dedup gemvs.
// New: K processed in 4 tiles of 16 with online softmax. Per tile, 4 lanes per
// neighbor row stream fp32 x once (score dot on the fly), stage fp16 in LDS
// (row = 160 dims incl. te), then wkv accumulates from the stage. x touched ONCE.
__global__ __launch_bounds__(256, 4)
void structure_learner_kernel(
    const float* __restrict__ x,
    const int*   __restrict__ target_node_ids,
    const int*   __restrict__ target_node_times,
    const int*   __restrict__ neighbor_ids,
    const int*   __restrict__ edge_time,
    const float* __restrict__ edge_weight,
    const float* __restrict__ gumbel_u,
    const float* __restrict__ te_w,
    const float* __restrict__ te_b,
    const float* __restrict__ mlp_w,
    const float* __restrict__ mlp_b,
    const float* __restrict__ ws,
    const float* __restrict__ tetab,   // nullptr -> cos in-kernel
    float* __restrict__ out_ao,
    float* __restrict__ out_new,
    float* __restrict__ out_mask)
{
    __shared__ __attribute__((aligned(16))) _Float16 s_xh[ROWS][KT][XH_STRIDE];
    __shared__ __attribute__((aligned(16))) float s_qin[ROWS][LD];
    __shared__ __attribute__((aligned(16))) float s_qt[ROWS][LD];
    __shared__ __attribute__((aligned(16))) float s_wkv[ROWS][LD];
    __shared__ __attribute__((aligned(16))) float s_ao[ROWS][LD];
    __shared__ float s_aw[ROWS][KK];   // exp(s_k - m_tile) per k
    __shared__ float s_mt[ROWS][4];    // running max snapshot per tile
    __shared__ int   s_nid[ROWS][KK];
    __shared__ int   s_et[ROWS][KK];

    const int tid  = threadIdx.x;
    const int wr   = tid >> 6;   // wave == row
    const int lane = tid & 63;
    const int b    = blockIdx.x * ROWS + wr;

    const float* Mw = ws + WS_M;
    const float* V2 = ws + WS_V2;
    const float* Cv = ws + WS_C;
    const float* Uv = ws + WS_U;
    const float* B2 = ws + WS_B2;
    const float  s0 = ws[WS_S0];

    // ---- P0: meta + q_in ----
    {
        const long eb = (long)b * KK + lane;
        s_nid[wr][lane] = neighbor_ids[eb];
        s_et[wr][lane]  = edge_time[eb];
        const int tn = target_node_ids[b];
        const float2 tx = *(const float2*)(x + (long)tn * F_DIM + lane * 2);
        s_qin[wr][lane * 2]     = tx.x;
        s_qin[wr][lane * 2 + 1] = tx.y;
        if (lane < TE_DIM) {
            const int tt = target_node_times[b];
            s_qin[wr][F_DIM + lane] =
                (tetab && (unsigned)tt < (unsigned)TAB_T)
                    ? tetab[(long)tt * TE_DIM + lane]
                    : cosf(fmaf((float)tt, te_w[lane], te_b[lane]));
        }
    }
    __syncthreads();

    // ---- P1: q_tilde = M @ q_in + c ----
    gemv_rows(Mw, Cv, s_qin, s_qt, tid);
    __syncthreads();

    // ---- sbk = q_in . U + s0 (wave-uniform) ----
    float p = s_qin[wr][lane] * Uv[lane];
    p = fmaf(s_qin[wr][lane + 64], Uv[lane + 64], p);
    if (lane < 32) p = fmaf(s_qin[wr][128 + lane], Uv[128 + lane], p);
    const float sbk = wave_sum(p) + s0;

    // ---- K-tile loop: stream-score-stage (fp32 dot, fp16 stage), online SM ----
    const int q = lane >> 2;   // team 0..15 = staged row
    const int j = lane & 3;    // feature quarter
    float m_run = -3.0e38f, l_run = 0.f;
    float ax = 0.f, ay = 0.f, at = 0.f;

    for (int t = 0; t < 4; ++t) {
        const int k   = KT * t + q;
        const int nid = s_nid[wr][k];
        const int et  = s_et[wr][k];

        // stream x quarter: fp32 score dot + fp16 write-through stage
        const float4* xr  = (const float4*)(x + (long)nid * F_DIM + 32 * j);
        const float4* qt4 = (const float4*)(s_qt[wr] + 32 * j);
        _Float16* st = &s_xh[wr][q][32 * j];
        float a0 = 0.f, a1 = 0.f;
        #pragma unroll
        for (int f = 0; f < 8; f += 2) {
            const float4 A = xr[f], B = xr[f + 1];
            a0 = dot4acc(A, qt4[f],     a0);
            a1 = dot4acc(B, qt4[f + 1], a1);
            union { _Float16 hh[4]; unsigned long long u; } pa, pb;
            pa.hh[0] = (_Float16)A.x; pa.hh[1] = (_Float16)A.y;
            pa.hh[2] = (_Float16)A.z; pa.hh[3] = (_Float16)A.w;
            pb.hh[0] = (_Float16)B.x; pb.hh[1] = (_Float16)B.y;
            pb.hh[2] = (_Float16)B.z; pb.hh[3] = (_Float16)B.w;
            *(unsigned long long*)&st[4 * f]     = pa.u;
            *(unsigned long long*)&st[4 * f + 4] = pb.u;
        }
        float acc = a0 + a1;

        // te: 8 dims [8j, 8j+8) — fp32 in score, fp16 into stage
        {
            const float* qte = s_qt[wr] + F_DIM + 8 * j;
            _Float16* stt = &s_xh[wr][q][F_DIM + 8 * j];
            if (tetab && (unsigned)et < (unsigned)TAB_T) {
                const float4* tr = (const float4*)(tetab + (long)et * TE_DIM + 8 * j);
                const float4 T0 = tr[0], T1 = tr[1];
                acc = fmaf(T0.x, qte[0], acc);
                acc = fmaf(T0.y, qte[1], acc);
                acc = fmaf(T0.z, qte[2], acc);
                acc = fmaf(T0.w, qte[3], acc);
                acc = fmaf(T1.x, qte[4], acc);
                acc = fmaf(T1.y, qte[5], acc);
                acc = fmaf(T1.z, qte[6], acc);
                acc = fmaf(T1.w, qte[7], acc);
                union { _Float16 hh[4]; unsigned long long u; } p0, p1;
                p0.hh[0] = (_Float16)T0.x; p0.hh[1] = (_Float16)T0.y;
                p0.hh[2] = (_Float16)T0.z; p0.hh[3] = (_Float16)T0.w;
                p1.hh[0] = (_Float16)T1.x; p1.hh[1] = (_Float16)T1.y;
                p1.hh[2] = (_Float16)T1.z; p1.hh[3] = (_Float16)T1.w;
                *(unsigned long long*)&stt[0] = p0.u;
                *(unsigned long long*)&stt[4] = p1.u;
            } else {
                const float etv = (float)et;
                #pragma unroll
                for (int ii = 0; ii < 8; ++ii) {
                    const float cte = cosf(fmaf(etv, te_w[8 * j + ii], te_b[8 * j + ii]));
                    acc = fmaf(cte, qte[ii], acc);
                    stt[ii] = (_Float16)cte;
                }
            }
        }

        // 4-lane team reduce -> all 4 lanes hold the full score (bit-identical)
        acc += __shfl_xor(acc, 1, 64);
        acc += __shfl_xor(acc, 2, 64);
        const float sc = acc + sbk;

        // online softmax update (wave-uniform m, l)
        const float mt   = wave_max(sc);
        const float mnew = fmaxf(m_run, mt);
        const float cfac = expf(m_run - mnew);   // 0 on first tile
        const float e    = expf(sc - mnew);
        l_run = l_run * cfac + wave_sum(e) * 0.25f;  // each score duplicated 4x (exact)
        m_run = mnew;
        if (j == 0)    s_aw[wr][k]  = e;
        if (lane == 0) s_mt[wr][t]  = mnew;
        __syncthreads();   // stage + e visible (uniform across all 4 waves)

        // wkv accumulate from the LDS stage (lane = feature pair)
        ax *= cfac; ay *= cfac; at *= cfac;
        #pragma unroll
        for (int qq = 0; qq < KT; ++qq) {
            const float wgt = s_aw[wr][KT * t + qq];
            union { unsigned u; _Float16 h2[2]; } cc;
            cc.u = *(const unsigned*)&s_xh[wr][qq][2 * lane];
            ax = fmaf(wgt, (float)cc.h2[0], ax);
            ay = fmaf(wgt, (float)cc.h2[1], ay);
            if (lane < TE_DIM) at = fmaf(wgt, (float)s_xh[wr][qq][F_DIM + lane], at);
        }
        __syncthreads();   // stage may be overwritten next tile
    }

    // ---- finalize wkv = (sum e_k x_k) / l ----
    const float rl = 1.f / l_run;
    s_wkv[wr][lane * 2]     = ax * rl;
    s_wkv[wr][lane * 2 + 1] = ay * rl;
    if (lane < TE_DIM) s_wkv[wr][F_DIM + lane] = at * rl;

    // prefetch P5 inputs (hide under P4)
    const float u  = gumbel_u[(long)b * KK + lane];
    const float ew = edge_weight[(long)b * KK + lane];
    __syncthreads();

    // ---- P4: ao = V2 @ wkv + b2 ----
    gemv_rows(V2, B2, s_wkv, s_ao, tid);
    __syncthreads();

    // ---- P5: epilogue (wave per row, lane = k) ----
    {
        const float awk = s_aw[wr][lane] * expf(s_mt[wr][lane >> 4] - m_run) * rl;

        float pm = s_ao[wr][lane] * mlp_w[lane];
        pm = fmaf(s_ao[wr][lane + 64], mlp_w[lane + 64], pm);
        if (lane < 32) pm = fmaf(s_ao[wr][lane + 128], mlp_w[lane + 128], pm);
        const float base = wave_sum(pm) + mlp_b[0];

        float* ao = out_ao + (long)b * DD;
        ao[lane]      = s_ao[wr][lane];
        ao[lane + 64] = s_ao[wr][lane + 64];
        if (lane < 32) ao[lane + 128] = s_ao[wr][lane + 128];

        const float g = -logf(-logf(u + 1e-10f) + 1e-10f);
        const float z = awk + g;  // TAU = 1.0
        const float m = wave_max(z);
        const float e = expf(z - m);
        const float l = wave_sum(e);
        out_mask[(long)b * KK + lane] = (e / l > 0.2f) ? 1.0f : 0.0f;

        const float val = fmaf(ew, mlp_w[DD], base);
        out_new[(long)b * KK + lane] = (val >= 0.f) ? val : 0.01f * val;
    }
}

extern "C" void kernel_launch(void* const* d_in, const int* in_sizes, int n_in,
                              void* d_out, int out_size, void* d_ws, size_t ws_size,
                              hipStream_t stream) {
    const float* x   = (const float*)d_in[0];
    const int*   tni = (const int*)d_in[1];
    const int*   tnt = (const int*)d_in[2];
    const int*   nid = (const int*)d_in[3];
    const int*   et  = (const int*)d_in[4];
    const float* ew  = (const float*)d_in[5];
    const float* gu  = (const float*)d_in[6];
    const float* tew = (const float*)d_in[7];
    const float* teb = (const float*)d_in[8];
    const float* ipw = (const float*)d_in[9];
    const float* ipb = (const float*)d_in[10];
    const float* ow  = (const float*)d_in[11];
    const float* ob  = (const float*)d_in[12];
    const float* mw  = (const float*)d_in[13];
    const float* mb  = (const float*)d_in[14];

    float* wsf = (float*)d_ws;

    float* out      = (float*)d_out;
    float* out_ao   = out;
    float* out_new  = out + (long)NB * DD;
    float* out_mask = out + (long)NB * DD + (long)NB * KK;

    const bool use_tab = ws_size >= (size_t)(WS_TE + TAB_N) * sizeof(float);
    const int  setup_grid = SETUP_BASE + (use_tab ? TAB_BLOCKS : 0);

    setup_kernel<<<setup_grid, 256, 0, stream>>>(ipw, ipb, ow, ob, tew, teb, wsf);

    structure_learner_kernel<<<NB / ROWS, 256, 0, stream>>>(
        x, tni, tnt, nid, et, ew, gu, tew, teb, mw, mb, wsf,
        use_tab ? (wsf + WS_TE) : nullptr,
        out_ao, out_new, out_mask);
}